// Round 6
// baseline (1625.471 us; speedup 1.0000x reference)
//
#include <hip/hip_runtime.h>
#include <math.h>

#define D 256
#define TOK_B 16
#define TOK_T 8192
#define NTOK (TOK_B * TOK_T)
#define KSEL 100

// ---- scratch in device globals (d_ws untouched) ----
__device__ float g_txt[TOK_B * D];   // normalized text (f32, np semantics)
__device__ float g_obj[NTOK];        // obj sigmoid scores (f32)
__device__ int   g_sel[TOK_B * KSEL];

// ---------------------------------------------------------------------------
// numpy pairwise_sum emulation. n=256 -> sum128(a[0:128]) + sum128(a[128:256]);
// each 128-block uses numpy's 8-accumulator unrolled scheme.
// ---------------------------------------------------------------------------
template <typename F>
__device__ __forceinline__ float np_sum128_f(F f, int base) {
#pragma clang fp contract(off)
  float r0 = f(base + 0), r1 = f(base + 1), r2 = f(base + 2), r3 = f(base + 3);
  float r4 = f(base + 4), r5 = f(base + 5), r6 = f(base + 6), r7 = f(base + 7);
  for (int i = 8; i < 128; i += 8) {
    r0 += f(base + i + 0); r1 += f(base + i + 1);
    r2 += f(base + i + 2); r3 += f(base + i + 3);
    r4 += f(base + i + 4); r5 += f(base + i + 5);
    r6 += f(base + i + 6); r7 += f(base + i + 7);
  }
  return ((r0 + r1) + (r2 + r3)) + ((r4 + r5) + (r6 + r7));
}
template <typename F>
__device__ __forceinline__ float np_sum256_f(F f) {
#pragma clang fp contract(off)
  return np_sum128_f(f, 0) + np_sum128_f(f, 128);
}

// scipy-style gelu: f32 divide by f32(sqrt2), f64 erf, f32 compose
__device__ __forceinline__ float np_geluf(float x) {
#pragma clang fp contract(off)
  const float t = x / 1.41421356237309504880f;  // rounds to f32(sqrt(2))
  const float e = (float)erf((double)t);
  return (0.5f * x) * (1.0f + e);
}
__device__ __forceinline__ float np_sigmoidf(float x) {
#pragma clang fp contract(off)
  return 1.0f / (1.0f + expf(-x));
}

// ---------------------------------------------------------------------------
// K0: txt = text_emb / sqrt(np.sum(text^2) + 1e-12), all f32 np semantics.
// ---------------------------------------------------------------------------
__global__ __launch_bounds__(256) void k0_txt(const float* __restrict__ text_emb) {
#pragma clang fp contract(off)
  const int b = blockIdx.x, tid = threadIdx.x;
  __shared__ float sSq[D];
  __shared__ float sTot;
  const float e = text_emb[b * D + tid];
  sSq[tid] = e * e;
  __syncthreads();
  if (tid == 0) {
    const float* p = sSq;
    sTot = np_sum256_f([&](int i) { return p[i]; });
  }
  __syncthreads();
  g_txt[b * D + tid] = e / sqrtf(sTot + 1e-12f);
}

// ---------------------------------------------------------------------------
// accumulating GEMM microkernel: acc[4][8] += S[r0..r0+3][0:256] @ W[:,c0..c0+7]
// strictly ascending k, one f32 fma chain per C element (BLAS semantics).
// ---------------------------------------------------------------------------
__device__ __forceinline__ void gemm_acc(const float (*__restrict__ S)[D],
                                         const float* __restrict__ W, int r0,
                                         int c0, float acc[4][8]) {
  for (int k = 0; k < D; k += 4) {
    float4 A0 = *(const float4*)&S[r0 + 0][k];
    float4 A1 = *(const float4*)&S[r0 + 1][k];
    float4 A2 = *(const float4*)&S[r0 + 2][k];
    float4 A3 = *(const float4*)&S[r0 + 3][k];
    const float ar[4][4] = {{A0.x, A0.y, A0.z, A0.w},
                            {A1.x, A1.y, A1.z, A1.w},
                            {A2.x, A2.y, A2.z, A2.w},
                            {A3.x, A3.y, A3.z, A3.w}};
#pragma unroll
    for (int kk = 0; kk < 4; ++kk) {
      const float* wr = W + (size_t)(k + kk) * D + c0;
      float4 W0 = *(const float4*)wr;
      float4 W1 = *(const float4*)(wr + 4);
      const float wv[8] = {W0.x, W0.y, W0.z, W0.w, W1.x, W1.y, W1.z, W1.w};
#pragma unroll
      for (int i = 0; i < 4; ++i)
#pragma unroll
        for (int j = 0; j < 8; ++j)
          acc[i][j] = fmaf(ar[i][kk], wv[j], acc[i][j]);
    }
  }
}

// ---------------------------------------------------------------------------
// K1: obj scores for all tokens, faithful np-f32 semantics.
// 32 tokens/block, 256 threads (8 row-groups x 32 col-groups, 4x8 microtile).
// GEMM1 runs the FULL 512-k chain: vision k=0..255 then text k=256..511.
// ---------------------------------------------------------------------------
__global__ __launch_bounds__(256) void k1_obj(
    const float* __restrict__ vision, const float* __restrict__ fuse_w1,
    const float* __restrict__ fuse_b1, const float* __restrict__ fuse_w2,
    const float* __restrict__ fuse_b2, const float* __restrict__ obj_ln_g,
    const float* __restrict__ obj_ln_b, const float* __restrict__ obj_w1,
    const float* __restrict__ obj_b1, const float* __restrict__ obj_w2,
    const float* __restrict__ obj_b2) {
#pragma clang fp contract(off)
  const int tid = threadIdx.x;
  const int tr = tid >> 5, tc = tid & 31;
  const int r0 = tr << 2, c0 = tc << 3;
  const int blk = blockIdx.x;
  const int batch = blk >> 8;  // 256 blocks per batch

  __shared__ float sA[32][D];   // vision tile -> h -> q
  __shared__ float sB[32][D];   // gelu1 -> oh
  __shared__ float sTxt[D];
  __shared__ float sMu[32], sRstd[32];

  // stage vision tile + txt row
  {
    const float* src = vision + (size_t)blk * (32 * D);
    float* dst = &sA[0][0];
#pragma unroll
    for (int i = 0; i < 8; ++i) {
      const int off = i * 1024 + tid * 4;
      *(float4*)(dst + off) = *(const float4*)(src + off);
    }
    sTxt[tid] = g_txt[batch * D + tid];
  }
  __syncthreads();

  float acc[4][8];
#pragma unroll
  for (int i = 0; i < 4; ++i)
#pragma unroll
    for (int j = 0; j < 8; ++j) acc[i][j] = 0.0f;

  // GEMM1 part A: vision rows, k = 0..255 (ascending)
  gemm_acc(sA, fuse_w1, r0, c0, acc);
  // GEMM1 part B: text rows, k = 256..511 (ascending; same tv for all rows)
  for (int k = 0; k < D; ++k) {
    const float tv = sTxt[k];
    const float* wr = fuse_w1 + (size_t)(D + k) * D + c0;
    float4 W0 = *(const float4*)wr;
    float4 W1 = *(const float4*)(wr + 4);
    const float wv[8] = {W0.x, W0.y, W0.z, W0.w, W1.x, W1.y, W1.z, W1.w};
#pragma unroll
    for (int i = 0; i < 4; ++i)
#pragma unroll
      for (int j = 0; j < 8; ++j) acc[i][j] = fmaf(tv, wv[j], acc[i][j]);
  }
  // + b1, gelu (np semantics) -> sB
  {
#pragma unroll
    for (int j2 = 0; j2 < 8; ++j2) {
      const float b = fuse_b1[c0 + j2];
#pragma unroll
      for (int i = 0; i < 4; ++i) {
        const float v = np_geluf(acc[i][j2] + b);
        sB[r0 + i][c0 + j2] = v;
      }
    }
  }
  __syncthreads();

  // GEMM2: h = gelu1 @ w2 + b2 -> sA
#pragma unroll
  for (int i = 0; i < 4; ++i)
#pragma unroll
    for (int j = 0; j < 8; ++j) acc[i][j] = 0.0f;
  gemm_acc(sB, fuse_w2, r0, c0, acc);
  {
#pragma unroll
    for (int j2 = 0; j2 < 8; ++j2) {
      const float b = fuse_b2[c0 + j2];
#pragma unroll
      for (int i = 0; i < 4; ++i) sA[r0 + i][c0 + j2] = acc[i][j2] + b;
    }
  }
  __syncthreads();

  // LN stats, numpy pairwise: mu = mean(h), var = mean((h-mu)^2)
  if (tid < 32) {
    const float* hrow = &sA[tid][0];
    const float mu = np_sum256_f([&](int i) { return hrow[i]; }) / 256.0f;
    const float var = np_sum256_f([&](int i) {
                        const float d = hrow[i] - mu;
                        return d * d;
                      }) / 256.0f;
    sMu[tid] = mu;
    sRstd[tid] = 1.0f / sqrtf(var + 1e-5f);
  }
  __syncthreads();

  // oh = ((h-mu)*rstd)*g + b  -> sB
  {
    const float lg = obj_ln_g[tid], lb = obj_ln_b[tid];
    for (int r = 0; r < 32; ++r) {
      const float t = (sA[r][tid] - sMu[r]) * sRstd[r];
      sB[r][tid] = t * lg + lb;
    }
  }
  __syncthreads();

  // obj head GEMM: q = gelu(oh @ ow1 + ob1) -> sA
#pragma unroll
  for (int i = 0; i < 4; ++i)
#pragma unroll
    for (int j = 0; j < 8; ++j) acc[i][j] = 0.0f;
  gemm_acc(sB, obj_w1, r0, c0, acc);
  {
#pragma unroll
    for (int j2 = 0; j2 < 8; ++j2) {
      const float b = obj_b1[c0 + j2];
#pragma unroll
      for (int i = 0; i < 4; ++i)
        sA[r0 + i][c0 + j2] = np_geluf(acc[i][j2] + b);
    }
  }
  __syncthreads();

  // logit = (q . ow2) + ob2, sequential ascending fma (sgemv semantics)
  if (tid < 32) {
    const float* q = &sA[tid][0];
    float L = 0.0f;
    for (int k = 0; k < D; ++k) L = fmaf(q[k], obj_w2[k], L);
    L = L + obj_b2[0];
    g_obj[(size_t)blk * 32 + tid] = np_sigmoidf(L);
  }
}

// ---------------------------------------------------------------------------
// K2: per-batch top-100 directly on f32 scores; exact np.top_k semantics
// (descending score, ties -> lowest index) via packed u64 keys.
// ---------------------------------------------------------------------------
__global__ __launch_bounds__(256) void k2_topk(float* __restrict__ out_scores) {
  const int b = blockIdx.x, tid = threadIdx.x;
  __shared__ unsigned long long sKey[TOK_T];
  __shared__ unsigned long long sRed[4];
  for (int i = tid; i < TOK_T; i += 256) {
    const float s = g_obj[b * TOK_T + i];
    sKey[i] = ((unsigned long long)__float_as_uint(s) << 32) |
              (unsigned)(TOK_T - 1 - i);
  }
  __syncthreads();
  for (int rank = 0; rank < KSEL; ++rank) {
    unsigned long long m = 0ull;
    for (int i = tid; i < TOK_T; i += 256) {
      const unsigned long long v = sKey[i];
      m = v > m ? v : m;
    }
#pragma unroll
    for (int off = 32; off > 0; off >>= 1) {
      const unsigned long long o = __shfl_down(m, off, 64);
      m = o > m ? o : m;
    }
    if ((tid & 63) == 0) sRed[tid >> 6] = m;
    __syncthreads();
    if (tid == 0) {
      unsigned long long w = sRed[0];
#pragma unroll
      for (int i = 1; i < 4; ++i) w = sRed[i] > w ? sRed[i] : w;
      const int idx = (TOK_T - 1) - (int)(unsigned)(w & 0xFFFFFFFFull);
      out_scores[b * KSEL + rank] = __uint_as_float((unsigned)(w >> 32));
      g_sel[b * KSEL + rank] = idx;
      sKey[idx] = 0ull;
    }
    __syncthreads();
  }
}

// ---------------------------------------------------------------------------
// K3: box head + text scores for the 1600 selected tokens, np-f32 semantics.
// 8 tokens/block, 256 threads (thread = output column).
// ---------------------------------------------------------------------------
__global__ __launch_bounds__(256) void k3_box(
    const float* __restrict__ vision, const float* __restrict__ fuse_w1,
    const float* __restrict__ fuse_b1, const float* __restrict__ fuse_w2,
    const float* __restrict__ fuse_b2, const float* __restrict__ box_ln_g,
    const float* __restrict__ box_ln_b, const float* __restrict__ box_w1,
    const float* __restrict__ box_b1, const float* __restrict__ box_w2,
    const float* __restrict__ box_b2, float* __restrict__ out) {
#pragma clang fp contract(off)
  const int tid = threadIdx.x, c = tid;
  __shared__ float sV[8][D];    // vision -> q(box)
  __shared__ float sG[8][D];    // gelu1 -> bh
  __shared__ float sH[8][D];    // h
  __shared__ float sTx[8][D];   // per-token txt row
  __shared__ float sMu[8], sRstd[8];
  __shared__ int sIdx[8], sBat[8];
  if (tid < 8) {
    const int e = blockIdx.x * 8 + tid;
    sBat[tid] = e / KSEL;
    sIdx[tid] = g_sel[e];
  }
  __syncthreads();
  {
    const int u = tid >> 5, col = (tid & 31) * 8;
    const float* src = vision + ((size_t)sBat[u] * TOK_T + sIdx[u]) * D + col;
    *(float4*)&sV[u][col] = *(const float4*)src;
    *(float4*)&sV[u][col + 4] = *(const float4*)(src + 4);
    const float* tsrc = &g_txt[sBat[u] * D + col];
    *(float4*)&sTx[u][col] = *(const float4*)tsrc;
    *(float4*)&sTx[u][col + 4] = *(const float4*)(tsrc + 4);
  }
  __syncthreads();

  float acc[8];
#pragma unroll
  for (int u = 0; u < 8; ++u) acc[u] = 0.0f;
  // GEMM1: k = 0..255 vision, then k = 256..511 text (ascending)
  for (int k = 0; k < D; ++k) {
    const float w = fuse_w1[k * D + c];
#pragma unroll
    for (int u = 0; u < 8; ++u) acc[u] = fmaf(sV[u][k], w, acc[u]);
  }
  for (int k = 0; k < D; ++k) {
    const float w = fuse_w1[(D + k) * D + c];
#pragma unroll
    for (int u = 0; u < 8; ++u) acc[u] = fmaf(sTx[u][k], w, acc[u]);
  }
  {
    const float b = fuse_b1[c];
#pragma unroll
    for (int u = 0; u < 8; ++u) sG[u][c] = np_geluf(acc[u] + b);
  }
  __syncthreads();

  // GEMM2 -> h
#pragma unroll
  for (int u = 0; u < 8; ++u) acc[u] = 0.0f;
  for (int k = 0; k < D; ++k) {
    const float w = fuse_w2[k * D + c];
#pragma unroll
    for (int u = 0; u < 8; ++u) acc[u] = fmaf(sG[u][k], w, acc[u]);
  }
  {
    const float b = fuse_b2[c];
#pragma unroll
    for (int u = 0; u < 8; ++u) sH[u][c] = acc[u] + b;
  }
  __syncthreads();

  // per-token stats (np pairwise) + text score
  if (tid < 8) {
    const int u = tid;
    const float* h = &sH[u][0];
    const float* tx = &sTx[u][0];
    const float mu = np_sum256_f([&](int i) { return h[i]; }) / 256.0f;
    const float var = np_sum256_f([&](int i) {
                        const float d = h[i] - mu;
                        return d * d;
                      }) / 256.0f;
    sMu[u] = mu;
    sRstd[u] = 1.0f / sqrtf(var + 1e-5f);
    const float q2 = np_sum256_f([&](int i) { return h[i] * h[i]; });
    const float den = sqrtf(q2 + 1e-12f);
    const float ts = np_sum256_f([&](int i) { return (h[i] / den) * tx[i]; });
    out[8000 + blockIdx.x * 8 + u] = ts;
  }
  __syncthreads();

  // bh -> sG
  {
    const float lg = box_ln_g[c], lb = box_ln_b[c];
#pragma unroll
    for (int u = 0; u < 8; ++u) {
      const float t = (sH[u][c] - sMu[u]) * sRstd[u];
      sG[u][c] = t * lg + lb;
    }
  }
  __syncthreads();

  // box GEMM: q = gelu(bh @ bw1 + bb1) -> sV
#pragma unroll
  for (int u = 0; u < 8; ++u) acc[u] = 0.0f;
  for (int k = 0; k < D; ++k) {
    const float w = box_w1[k * D + c];
#pragma unroll
    for (int u = 0; u < 8; ++u) acc[u] = fmaf(sG[u][k], w, acc[u]);
  }
  {
    const float b = box_b1[c];
#pragma unroll
    for (int u = 0; u < 8; ++u) sV[u][c] = np_geluf(acc[u] + b);
  }
  __syncthreads();

  // logits: sequential ascending fma per (token, j), then + b2, sigmoid
  if (tid < 32) {
    const int u = tid >> 2, j = tid & 3;
    const float* q = &sV[u][0];
    float L = 0.0f;
    for (int k = 0; k < D; ++k) L = fmaf(q[k], box_w2[k * 4 + j], L);
    L = L + box_b2[j];
    out[(blockIdx.x * 8 + u) * 4 + j] = np_sigmoidf(L);
  }
}

extern "C" void kernel_launch(void* const* d_in, const int* in_sizes, int n_in,
                              void* d_out, int out_size, void* d_ws,
                              size_t ws_size, hipStream_t stream) {
  const float* vision   = (const float*)d_in[0];
  const float* text_emb = (const float*)d_in[1];
  const float* fuse_w1  = (const float*)d_in[2];
  const float* fuse_b1  = (const float*)d_in[3];
  const float* fuse_w2  = (const float*)d_in[4];
  const float* fuse_b2  = (const float*)d_in[5];
  const float* box_ln_g = (const float*)d_in[6];
  const float* box_ln_b = (const float*)d_in[7];
  const float* box_w1   = (const float*)d_in[8];
  const float* box_b1   = (const float*)d_in[9];
  const float* box_w2   = (const float*)d_in[10];
  const float* box_b2   = (const float*)d_in[11];
  const float* obj_ln_g = (const float*)d_in[12];
  const float* obj_ln_b = (const float*)d_in[13];
  const float* obj_w1   = (const float*)d_in[14];
  const float* obj_b1   = (const float*)d_in[15];
  const float* obj_w2   = (const float*)d_in[16];
  const float* obj_b2   = (const float*)d_in[17];
  float* out = (float*)d_out;

  k0_txt<<<TOK_B, 256, 0, stream>>>(text_emb);
  k1_obj<<<NTOK / 32, 256, 0, stream>>>(
      vision, fuse_w1, fuse_b1, fuse_w2, fuse_b2, obj_ln_g, obj_ln_b, obj_w1,
      obj_b1, obj_w2, obj_b2);
  k2_topk<<<TOK_B, 256, 0, stream>>>(out + 6400);
  k3_box<<<(TOK_B * KSEL) / 8, 256, 0, stream>>>(
      vision, fuse_w1, fuse_b1, fuse_w2, fuse_b2, box_ln_g, box_ln_b, box_w1,
      box_b1, box_w2, box_b2, out);
}

// Round 7
// 1574.566 us; speedup vs baseline: 1.0323x; 1.0323x over previous
//
#include <hip/hip_runtime.h>
#include <math.h>

#define D 256
#define PD 260  // padded LDS row: 260 % 4 == 0 (float4-aligned), 260 % 32 == 4 (bank shift)
#define TOK_B 16
#define TOK_T 8192
#define NTOK (TOK_B * TOK_T)
#define KSEL 100

// ---- scratch in device globals (d_ws untouched) ----
__device__ float g_txt[TOK_B * D];   // normalized text (f32, np semantics)
__device__ float g_obj[NTOK];        // obj sigmoid scores (f32)
__device__ int   g_sel[TOK_B * KSEL];

// ---------------------------------------------------------------------------
// numpy pairwise_sum emulation (serial form, used by K0/K3).
// n=256 -> sum128(a[0:128]) + sum128(a[128:256]); each 128-block uses numpy's
// 8-accumulator unrolled scheme.
// ---------------------------------------------------------------------------
template <typename F>
__device__ __forceinline__ float np_sum128_f(F f, int base) {
#pragma clang fp contract(off)
  float r0 = f(base + 0), r1 = f(base + 1), r2 = f(base + 2), r3 = f(base + 3);
  float r4 = f(base + 4), r5 = f(base + 5), r6 = f(base + 6), r7 = f(base + 7);
  for (int i = 8; i < 128; i += 8) {
    r0 += f(base + i + 0); r1 += f(base + i + 1);
    r2 += f(base + i + 2); r3 += f(base + i + 3);
    r4 += f(base + i + 4); r5 += f(base + i + 5);
    r6 += f(base + i + 6); r7 += f(base + i + 7);
  }
  return ((r0 + r1) + (r2 + r3)) + ((r4 + r5) + (r6 + r7));
}
template <typename F>
__device__ __forceinline__ float np_sum256_f(F f) {
#pragma clang fp contract(off)
  return np_sum128_f(f, 0) + np_sum128_f(f, 128);
}

// ---------------------------------------------------------------------------
// Parallel np pairwise sum over one 256-float LDS row: 8 lanes (j = lane&7),
// each computes numpy accumulator r_j of both 128-halves in exact np order,
// then the exact np combine tree via shfl_xor (f32 add is commutative, so
// every lane's tree value is bit-identical to np's). Returns full sum on all
// 8 lanes. F maps element index -> f32 term.
// ---------------------------------------------------------------------------
template <typename F>
__device__ __forceinline__ float np_sum256_par8(F f, int j) {
#pragma clang fp contract(off)
  float s0 = f(j);
  for (int i = 1; i < 16; ++i) s0 += f(8 * i + j);
  float s1 = f(128 + j);
  for (int i = 1; i < 16; ++i) s1 += f(128 + 8 * i + j);
  s0 += __shfl_xor(s0, 1);
  s0 += __shfl_xor(s0, 2);
  s0 += __shfl_xor(s0, 4);
  s1 += __shfl_xor(s1, 1);
  s1 += __shfl_xor(s1, 2);
  s1 += __shfl_xor(s1, 4);
  return s0 + s1;
}

// scipy-style gelu: f32 divide by f32(sqrt2), f64 erf, f32 compose
__device__ __forceinline__ float np_geluf(float x) {
#pragma clang fp contract(off)
  const float t = x / 1.41421356237309504880f;  // rounds to f32(sqrt(2))
  const float e = (float)erf((double)t);
  return (0.5f * x) * (1.0f + e);
}
__device__ __forceinline__ float np_sigmoidf(float x) {
#pragma clang fp contract(off)
  return 1.0f / (1.0f + expf(-x));
}

// ---------------------------------------------------------------------------
// K0: txt = text_emb / sqrt(np.sum(text^2) + 1e-12), all f32 np semantics.
// ---------------------------------------------------------------------------
__global__ __launch_bounds__(256) void k0_txt(const float* __restrict__ text_emb) {
#pragma clang fp contract(off)
  const int b = blockIdx.x, tid = threadIdx.x;
  __shared__ float sSq[D];
  __shared__ float sTot;
  const float e = text_emb[b * D + tid];
  sSq[tid] = e * e;
  __syncthreads();
  if (tid == 0) {
    const float* p = sSq;
    sTot = np_sum256_f([&](int i) { return p[i]; });
  }
  __syncthreads();
  g_txt[b * D + tid] = e / sqrtf(sTot + 1e-12f);
}

// ---------------------------------------------------------------------------
// accumulating GEMM microkernel (padded-row operand):
// acc[4][8] += S[r0..r0+3][0:256] @ W[:, c0..c0+7], strictly ascending k,
// one f32 fma chain per C element (matches np bit-exactly — verified R6).
// ---------------------------------------------------------------------------
__device__ __forceinline__ void gemm_acc(const float (*__restrict__ S)[PD],
                                         const float* __restrict__ W, int r0,
                                         int c0, float acc[4][8]) {
  for (int k = 0; k < D; k += 4) {
    float4 A0 = *(const float4*)&S[r0 + 0][k];
    float4 A1 = *(const float4*)&S[r0 + 1][k];
    float4 A2 = *(const float4*)&S[r0 + 2][k];
    float4 A3 = *(const float4*)&S[r0 + 3][k];
    const float ar[4][4] = {{A0.x, A0.y, A0.z, A0.w},
                            {A1.x, A1.y, A1.z, A1.w},
                            {A2.x, A2.y, A2.z, A2.w},
                            {A3.x, A3.y, A3.z, A3.w}};
#pragma unroll
    for (int kk = 0; kk < 4; ++kk) {
      const float* wr = W + (size_t)(k + kk) * D + c0;
      float4 W0 = *(const float4*)wr;
      float4 W1 = *(const float4*)(wr + 4);
      const float wv[8] = {W0.x, W0.y, W0.z, W0.w, W1.x, W1.y, W1.z, W1.w};
#pragma unroll
      for (int i = 0; i < 4; ++i)
#pragma unroll
        for (int j = 0; j < 8; ++j)
          acc[i][j] = fmaf(ar[i][kk], wv[j], acc[i][j]);
    }
  }
}

// ---------------------------------------------------------------------------
// K1: obj scores for all tokens, bit-exact np-f32 semantics.
// 32 tokens/block, 256 threads (8 row-groups x 32 col-groups, 4x8 microtile).
// Round-7 changes vs R6 (scheduling only, same arithmetic):
//  - LDS rows padded to PD=260 (kills same-bank row-serial conflicts)
//  - LN stats parallelized 8 lanes/row via np_sum256_par8 (exact np order)
//  - logit threads spread across all 4 waves (tid&7==0), conflict-free reads
// ---------------------------------------------------------------------------
__global__ __launch_bounds__(256) void k1_obj(
    const float* __restrict__ vision, const float* __restrict__ fuse_w1,
    const float* __restrict__ fuse_b1, const float* __restrict__ fuse_w2,
    const float* __restrict__ fuse_b2, const float* __restrict__ obj_ln_g,
    const float* __restrict__ obj_ln_b, const float* __restrict__ obj_w1,
    const float* __restrict__ obj_b1, const float* __restrict__ obj_w2,
    const float* __restrict__ obj_b2) {
#pragma clang fp contract(off)
  const int tid = threadIdx.x;
  const int tr = tid >> 5, tc = tid & 31;
  const int r0 = tr << 2, c0 = tc << 3;
  const int blk = blockIdx.x;
  const int batch = blk >> 8;  // 256 blocks per batch

  __shared__ float sA[32][PD];   // vision tile -> h -> q
  __shared__ float sB[32][PD];   // gelu1 -> oh
  __shared__ float sTxt[D];
  __shared__ float sMu[32], sRstd[32];

  // stage vision tile + txt row (pad-aware)
  {
    const float* src = vision + (size_t)blk * (32 * D);
#pragma unroll
    for (int i = 0; i < 8; ++i) {
      const int e = i * 1024 + tid * 4;
      const int row = e >> 8, col = e & 255;
      *(float4*)&sA[row][col] = *(const float4*)(src + e);
    }
    sTxt[tid] = g_txt[batch * D + tid];
  }
  __syncthreads();

  float acc[4][8];
#pragma unroll
  for (int i = 0; i < 4; ++i)
#pragma unroll
    for (int j = 0; j < 8; ++j) acc[i][j] = 0.0f;

  // GEMM1 part A: vision rows, k = 0..255 (ascending)
  gemm_acc(sA, fuse_w1, r0, c0, acc);
  // GEMM1 part B: text rows, k = 256..511 (ascending; same tv for all rows)
  for (int k = 0; k < D; ++k) {
    const float tv = sTxt[k];
    const float* wr = fuse_w1 + (size_t)(D + k) * D + c0;
    float4 W0 = *(const float4*)wr;
    float4 W1 = *(const float4*)(wr + 4);
    const float wv[8] = {W0.x, W0.y, W0.z, W0.w, W1.x, W1.y, W1.z, W1.w};
#pragma unroll
    for (int i = 0; i < 4; ++i)
#pragma unroll
      for (int j = 0; j < 8; ++j) acc[i][j] = fmaf(tv, wv[j], acc[i][j]);
  }
  // + b1, gelu (np semantics) -> sB
  {
#pragma unroll
    for (int j2 = 0; j2 < 8; ++j2) {
      const float b = fuse_b1[c0 + j2];
#pragma unroll
      for (int i = 0; i < 4; ++i)
        sB[r0 + i][c0 + j2] = np_geluf(acc[i][j2] + b);
    }
  }
  __syncthreads();

  // GEMM2: h = gelu1 @ w2 + b2 -> sA
#pragma unroll
  for (int i = 0; i < 4; ++i)
#pragma unroll
    for (int j = 0; j < 8; ++j) acc[i][j] = 0.0f;
  gemm_acc(sB, fuse_w2, r0, c0, acc);
  {
#pragma unroll
    for (int j2 = 0; j2 < 8; ++j2) {
      const float b = fuse_b2[c0 + j2];
#pragma unroll
      for (int i = 0; i < 4; ++i) sA[r0 + i][c0 + j2] = acc[i][j2] + b;
    }
  }
  __syncthreads();

  // LN stats, numpy pairwise, 8 lanes per row (exact np order)
  {
    const int r = tid >> 3, j = tid & 7;
    const float* hrow = &sA[r][0];
    const float mu =
        np_sum256_par8([&](int i) { return hrow[i]; }, j) / 256.0f;
    const float var = np_sum256_par8(
                          [&](int i) {
                            const float d = hrow[i] - mu;
                            return d * d;
                          },
                          j) /
                      256.0f;
    if (j == 0) {
      sMu[r] = mu;
      sRstd[r] = 1.0f / sqrtf(var + 1e-5f);
    }
  }
  __syncthreads();

  // oh = ((h-mu)*rstd)*g + b  -> sB  (column-parallel, conflict-free)
  {
    const float lg = obj_ln_g[tid], lb = obj_ln_b[tid];
    for (int r = 0; r < 32; ++r) {
      const float t = (sA[r][tid] - sMu[r]) * sRstd[r];
      sB[r][tid] = t * lg + lb;
    }
  }
  __syncthreads();

  // obj head GEMM: q = gelu(oh @ ow1 + ob1) -> sA
#pragma unroll
  for (int i = 0; i < 4; ++i)
#pragma unroll
    for (int j = 0; j < 8; ++j) acc[i][j] = 0.0f;
  gemm_acc(sB, obj_w1, r0, c0, acc);
  {
#pragma unroll
    for (int j2 = 0; j2 < 8; ++j2) {
      const float b = obj_b1[c0 + j2];
#pragma unroll
      for (int i = 0; i < 4; ++i)
        sA[r0 + i][c0 + j2] = np_geluf(acc[i][j2] + b);
    }
  }
  __syncthreads();

  // logit = (q . ow2) + ob2, sequential ascending fma (np semantics).
  // One thread per row, spread across all 4 waves; with PD pad the 8 active
  // lanes of each wave read distinct banks.
  if ((tid & 7) == 0) {
    const int row = tid >> 3;
    const float* q = &sA[row][0];
    float L = 0.0f;
    for (int k = 0; k < D; ++k) L = fmaf(q[k], obj_w2[k], L);
    L = L + obj_b2[0];
    g_obj[(size_t)blk * 32 + row] = np_sigmoidf(L);
  }
}

// ---------------------------------------------------------------------------
// K2: per-batch top-100 directly on f32 scores; exact np.top_k semantics
// (descending score, ties -> lowest index) via packed u64 keys.
// ---------------------------------------------------------------------------
__global__ __launch_bounds__(256) void k2_topk(float* __restrict__ out_scores) {
  const int b = blockIdx.x, tid = threadIdx.x;
  __shared__ unsigned long long sKey[TOK_T];
  __shared__ unsigned long long sRed[4];
  for (int i = tid; i < TOK_T; i += 256) {
    const float s = g_obj[b * TOK_T + i];
    sKey[i] = ((unsigned long long)__float_as_uint(s) << 32) |
              (unsigned)(TOK_T - 1 - i);
  }
  __syncthreads();
  for (int rank = 0; rank < KSEL; ++rank) {
    unsigned long long m = 0ull;
    for (int i = tid; i < TOK_T; i += 256) {
      const unsigned long long v = sKey[i];
      m = v > m ? v : m;
    }
#pragma unroll
    for (int off = 32; off > 0; off >>= 1) {
      const unsigned long long o = __shfl_down(m, off, 64);
      m = o > m ? o : m;
    }
    if ((tid & 63) == 0) sRed[tid >> 6] = m;
    __syncthreads();
    if (tid == 0) {
      unsigned long long w = sRed[0];
#pragma unroll
      for (int i = 1; i < 4; ++i) w = sRed[i] > w ? sRed[i] : w;
      const int idx = (TOK_T - 1) - (int)(unsigned)(w & 0xFFFFFFFFull);
      out_scores[b * KSEL + rank] = __uint_as_float((unsigned)(w >> 32));
      g_sel[b * KSEL + rank] = idx;
      sKey[idx] = 0ull;
    }
    __syncthreads();
  }
}

// ---------------------------------------------------------------------------
// K3: box head + text scores for the 1600 selected tokens, np-f32 semantics.
// 8 tokens/block, 256 threads (thread = output column). Rows padded to PD so
// the tid<8 row-serial sums read distinct banks.
// ---------------------------------------------------------------------------
__global__ __launch_bounds__(256) void k3_box(
    const float* __restrict__ vision, const float* __restrict__ fuse_w1,
    const float* __restrict__ fuse_b1, const float* __restrict__ fuse_w2,
    const float* __restrict__ fuse_b2, const float* __restrict__ box_ln_g,
    const float* __restrict__ box_ln_b, const float* __restrict__ box_w1,
    const float* __restrict__ box_b1, const float* __restrict__ box_w2,
    const float* __restrict__ box_b2, float* __restrict__ out) {
#pragma clang fp contract(off)
  const int tid = threadIdx.x, c = tid;
  __shared__ float sV[8][PD];    // vision -> q(box)
  __shared__ float sG[8][PD];    // gelu1 -> bh
  __shared__ float sH[8][PD];    // h
  __shared__ float sTx[8][PD];   // per-token txt row
  __shared__ float sMu[8], sRstd[8];
  __shared__ int sIdx[8], sBat[8];
  if (tid < 8) {
    const int e = blockIdx.x * 8 + tid;
    sBat[tid] = e / KSEL;
    sIdx[tid] = g_sel[e];
  }
  __syncthreads();
  {
    const int u = tid >> 5, col = (tid & 31) * 8;
    const float* src = vision + ((size_t)sBat[u] * TOK_T + sIdx[u]) * D + col;
    *(float4*)&sV[u][col] = *(const float4*)src;
    *(float4*)&sV[u][col + 4] = *(const float4*)(src + 4);
    const float* tsrc = &g_txt[sBat[u] * D + col];
    *(float4*)&sTx[u][col] = *(const float4*)tsrc;
    *(float4*)&sTx[u][col + 4] = *(const float4*)(tsrc + 4);
  }
  __syncthreads();

  float acc[8];
#pragma unroll
  for (int u = 0; u < 8; ++u) acc[u] = 0.0f;
  // GEMM1: k = 0..255 vision, then k = 256..511 text (ascending)
  for (int k = 0; k < D; ++k) {
    const float w = fuse_w1[k * D + c];
#pragma unroll
    for (int u = 0; u < 8; ++u) acc[u] = fmaf(sV[u][k], w, acc[u]);
  }
  for (int k = 0; k < D; ++k) {
    const float w = fuse_w1[(D + k) * D + c];
#pragma unroll
    for (int u = 0; u < 8; ++u) acc[u] = fmaf(sTx[u][k], w, acc[u]);
  }
  {
    const float b = fuse_b1[c];
#pragma unroll
    for (int u = 0; u < 8; ++u) sG[u][c] = np_geluf(acc[u] + b);
  }
  __syncthreads();

  // GEMM2 -> h
#pragma unroll
  for (int u = 0; u < 8; ++u) acc[u] = 0.0f;
  for (int k = 0; k < D; ++k) {
    const float w = fuse_w2[k * D + c];
#pragma unroll
    for (int u = 0; u < 8; ++u) acc[u] = fmaf(sG[u][k], w, acc[u]);
  }
  {
    const float b = fuse_b2[c];
#pragma unroll
    for (int u = 0; u < 8; ++u) sH[u][c] = acc[u] + b;
  }
  __syncthreads();

  // per-token stats (np pairwise) + text score
  if (tid < 8) {
    const int u = tid;
    const float* h = &sH[u][0];
    const float* tx = &sTx[u][0];
    const float mu = np_sum256_f([&](int i) { return h[i]; }) / 256.0f;
    const float var = np_sum256_f([&](int i) {
                        const float d = h[i] - mu;
                        return d * d;
                      }) / 256.0f;
    sMu[u] = mu;
    sRstd[u] = 1.0f / sqrtf(var + 1e-5f);
    const float q2 = np_sum256_f([&](int i) { return h[i] * h[i]; });
    const float den = sqrtf(q2 + 1e-12f);
    const float ts = np_sum256_f([&](int i) { return (h[i] / den) * tx[i]; });
    out[8000 + blockIdx.x * 8 + u] = ts;
  }
  __syncthreads();

  // bh -> sG
  {
    const float lg = box_ln_g[c], lb = box_ln_b[c];
#pragma unroll
    for (int u = 0; u < 8; ++u) {
      const float t = (sH[u][c] - sMu[u]) * sRstd[u];
      sG[u][c] = t * lg + lb;
    }
  }
  __syncthreads();

  // box GEMM: q = gelu(bh @ bw1 + bb1) -> sV
#pragma unroll
  for (int u = 0; u < 8; ++u) acc[u] = 0.0f;
  for (int k = 0; k < D; ++k) {
    const float w = box_w1[k * D + c];
#pragma unroll
    for (int u = 0; u < 8; ++u) acc[u] = fmaf(sG[u][k], w, acc[u]);
  }
  {
    const float b = box_b1[c];
#pragma unroll
    for (int u = 0; u < 8; ++u) sV[u][c] = np_geluf(acc[u] + b);
  }
  __syncthreads();

  // logits: sequential ascending fma per (token, j), then + b2, sigmoid
  if (tid < 32) {
    const int u = tid >> 2, j = tid & 3;
    const float* q = &sV[u][0];
    float L = 0.0f;
    for (int k = 0; k < D; ++k) L = fmaf(q[k], box_w2[k * 4 + j], L);
    L = L + box_b2[j];
    out[(blockIdx.x * 8 + u) * 4 + j] = np_sigmoidf(L);
  }
}

extern "C" void kernel_launch(void* const* d_in, const int* in_sizes, int n_in,
                              void* d_out, int out_size, void* d_ws,
                              size_t ws_size, hipStream_t stream) {
  const float* vision   = (const float*)d_in[0];
  const float* text_emb = (const float*)d_in[1];
  const float* fuse_w1  = (const float*)d_in[2];
  const float* fuse_b1  = (const float*)d_in[3];
  const float* fuse_w2  = (const float*)d_in[4];
  const float* fuse_b2  = (const float*)d_in[5];
  const float* box_ln_g = (const float*)d_in[6];
  const float* box_ln_b = (const float*)d_in[7];
  const float* box_w1   = (const float*)d_in[8];
  const float* box_b1   = (const float*)d_in[9];
  const float* box_w2   = (const float*)d_in[10];
  const float* box_b2   = (const float*)d_in[11];
  const float* obj_ln_g = (const float*)d_in[12];
  const float* obj_ln_b = (const float*)d_in[13];
  const float* obj_w1   = (const float*)d_in[14];
  const float* obj_b1   = (const float*)d_in[15];
  const float* obj_w2   = (const float*)d_in[16];
  const float* obj_b2   = (const float*)d_in[17];
  float* out = (float*)d_out;

  k0_txt<<<TOK_B, 256, 0, stream>>>(text_emb);
  k1_obj<<<NTOK / 32, 256, 0, stream>>>(
      vision, fuse_w1, fuse_b1, fuse_w2, fuse_b2, obj_ln_g, obj_ln_b, obj_w1,
      obj_b1, obj_w2, obj_b2);
  k2_topk<<<TOK_B, 256, 0, stream>>>(out + 6400);
  k3_box<<<(TOK_B * KSEL) / 8, 256, 0, stream>>>(
      vision, fuse_w1, fuse_b1, fuse_w2, fuse_b2, box_ln_g, box_ln_b, box_w1,
      box_b1, box_w2, box_b2, out);
}

// Round 8
// 1403.983 us; speedup vs baseline: 1.1578x; 1.1215x over previous
//
#include <hip/hip_runtime.h>
#include <math.h>

#define D 256
#define PD 260  // padded LDS row: %4==0 (float4-aligned), %32==4 (bank shift)
#define TOK_B 16
#define TOK_T 8192
#define NTOK (TOK_B * TOK_T)
#define KSEL 100

typedef unsigned long long ull;

// ---- scratch in device globals (d_ws untouched) ----
__device__ float g_txt[TOK_B * D];   // normalized text (f32, np semantics)
__device__ float g_obj[NTOK];        // obj sigmoid scores (f32)
__device__ int   g_sel[TOK_B * KSEL];

// ---------------------------------------------------------------------------
// numpy pairwise_sum emulation (serial form, used by K0).
// ---------------------------------------------------------------------------
template <typename F>
__device__ __forceinline__ float np_sum128_f(F f, int base) {
#pragma clang fp contract(off)
  float r0 = f(base + 0), r1 = f(base + 1), r2 = f(base + 2), r3 = f(base + 3);
  float r4 = f(base + 4), r5 = f(base + 5), r6 = f(base + 6), r7 = f(base + 7);
  for (int i = 8; i < 128; i += 8) {
    r0 += f(base + i + 0); r1 += f(base + i + 1);
    r2 += f(base + i + 2); r3 += f(base + i + 3);
    r4 += f(base + i + 4); r5 += f(base + i + 5);
    r6 += f(base + i + 6); r7 += f(base + i + 7);
  }
  return ((r0 + r1) + (r2 + r3)) + ((r4 + r5) + (r6 + r7));
}
template <typename F>
__device__ __forceinline__ float np_sum256_f(F f) {
#pragma clang fp contract(off)
  return np_sum128_f(f, 0) + np_sum128_f(f, 128);
}

// ---------------------------------------------------------------------------
// Parallel np pairwise sum: 8 lanes (j = lane&7) compute numpy accumulator
// r_j of both 128-halves in np order; combine tree via shfl_xor is
// bit-identical to np's ((r0+r1)+(r2+r3))+((r4+r5)+(r6+r7)).
// ---------------------------------------------------------------------------
template <typename F>
__device__ __forceinline__ float np_sum256_par8(F f, int j) {
#pragma clang fp contract(off)
  float s0 = f(j);
  for (int i = 1; i < 16; ++i) s0 += f(8 * i + j);
  float s1 = f(128 + j);
  for (int i = 1; i < 16; ++i) s1 += f(128 + 8 * i + j);
  s0 += __shfl_xor(s0, 1);
  s0 += __shfl_xor(s0, 2);
  s0 += __shfl_xor(s0, 4);
  s1 += __shfl_xor(s1, 1);
  s1 += __shfl_xor(s1, 2);
  s1 += __shfl_xor(s1, 4);
  return s0 + s1;
}

// scipy-style gelu: f32 divide by f32(sqrt2), f64 erf, f32 compose
__device__ __forceinline__ float np_geluf(float x) {
#pragma clang fp contract(off)
  const float t = x / 1.41421356237309504880f;
  const float e = (float)erf((double)t);
  return (0.5f * x) * (1.0f + e);
}
__device__ __forceinline__ float np_sigmoidf(float x) {
#pragma clang fp contract(off)
  return 1.0f / (1.0f + expf(-x));
}

// ---------------------------------------------------------------------------
// K0: txt = text_emb / sqrt(np.sum(text^2) + 1e-12), all f32 np semantics.
// ---------------------------------------------------------------------------
__global__ __launch_bounds__(256) void k0_txt(const float* __restrict__ text_emb) {
#pragma clang fp contract(off)
  const int b = blockIdx.x, tid = threadIdx.x;
  __shared__ float sSq[D];
  __shared__ float sTot;
  const float e = text_emb[b * D + tid];
  sSq[tid] = e * e;
  __syncthreads();
  if (tid == 0) {
    const float* p = sSq;
    sTot = np_sum256_f([&](int i) { return p[i]; });
  }
  __syncthreads();
  g_txt[b * D + tid] = e / sqrtf(sTot + 1e-12f);
}

// ---------------------------------------------------------------------------
// accumulating GEMM microkernel (padded-row operand):
// acc[4][8] += S[r0..r0+3][0:256] @ W[:, c0..c0+7], strictly ascending k,
// one f32 fma chain per C element (bit-exact vs np — verified R6).
// ---------------------------------------------------------------------------
__device__ __forceinline__ void gemm_acc(const float (*__restrict__ S)[PD],
                                         const float* __restrict__ W, int r0,
                                         int c0, float acc[4][8]) {
  for (int k = 0; k < D; k += 4) {
    float4 A0 = *(const float4*)&S[r0 + 0][k];
    float4 A1 = *(const float4*)&S[r0 + 1][k];
    float4 A2 = *(const float4*)&S[r0 + 2][k];
    float4 A3 = *(const float4*)&S[r0 + 3][k];
    const float ar[4][4] = {{A0.x, A0.y, A0.z, A0.w},
                            {A1.x, A1.y, A1.z, A1.w},
                            {A2.x, A2.y, A2.z, A2.w},
                            {A3.x, A3.y, A3.z, A3.w}};
#pragma unroll
    for (int kk = 0; kk < 4; ++kk) {
      const float* wr = W + (size_t)(k + kk) * D + c0;
      float4 W0 = *(const float4*)wr;
      float4 W1 = *(const float4*)(wr + 4);
      const float wv[8] = {W0.x, W0.y, W0.z, W0.w, W1.x, W1.y, W1.z, W1.w};
#pragma unroll
      for (int i = 0; i < 4; ++i)
#pragma unroll
        for (int j = 0; j < 8; ++j)
          acc[i][j] = fmaf(ar[i][kk], wv[j], acc[i][j]);
    }
  }
}

// ---------------------------------------------------------------------------
// K1: obj scores for all tokens, bit-exact np-f32 semantics.
// Round-8: single in-place 32xPD LDS buffer (34.8 KB -> 4 blocks/CU) for
// occupancy; extra __syncthreads separate read/write phases. Arithmetic
// unchanged vs R6/R7.
// ---------------------------------------------------------------------------
__global__ __launch_bounds__(256) void k1_obj(
    const float* __restrict__ vision, const float* __restrict__ fuse_w1,
    const float* __restrict__ fuse_b1, const float* __restrict__ fuse_w2,
    const float* __restrict__ fuse_b2, const float* __restrict__ obj_ln_g,
    const float* __restrict__ obj_ln_b, const float* __restrict__ obj_w1,
    const float* __restrict__ obj_b1, const float* __restrict__ obj_w2,
    const float* __restrict__ obj_b2) {
#pragma clang fp contract(off)
  const int tid = threadIdx.x;
  const int tr = tid >> 5, tc = tid & 31;
  const int r0 = tr << 2, c0 = tc << 3;
  const int blk = blockIdx.x;
  const int batch = blk >> 8;  // 256 blocks per batch

  __shared__ float sA[32][PD];  // vision -> gelu1 -> h -> oh -> q (in-place)
  __shared__ float sTxt[D];
  __shared__ float sMu[32], sRstd[32];

  // stage vision tile + txt row (pad-aware)
  {
    const float* src = vision + (size_t)blk * (32 * D);
#pragma unroll
    for (int i = 0; i < 8; ++i) {
      const int e = i * 1024 + tid * 4;
      const int row = e >> 8, col = e & 255;
      *(float4*)&sA[row][col] = *(const float4*)(src + e);
    }
    sTxt[tid] = g_txt[batch * D + tid];
  }
  __syncthreads();

  float acc[4][8];
#pragma unroll
  for (int i = 0; i < 4; ++i)
#pragma unroll
    for (int j = 0; j < 8; ++j) acc[i][j] = 0.0f;

  // GEMM1 part A: vision rows, k = 0..255 (ascending)
  gemm_acc(sA, fuse_w1, r0, c0, acc);
  // GEMM1 part B: text rows, k = 256..511 (ascending)
  for (int k = 0; k < D; ++k) {
    const float tv = sTxt[k];
    const float* wr = fuse_w1 + (size_t)(D + k) * D + c0;
    float4 W0 = *(const float4*)wr;
    float4 W1 = *(const float4*)(wr + 4);
    const float wv[8] = {W0.x, W0.y, W0.z, W0.w, W1.x, W1.y, W1.z, W1.w};
#pragma unroll
    for (int i = 0; i < 4; ++i)
#pragma unroll
      for (int j = 0; j < 8; ++j) acc[i][j] = fmaf(tv, wv[j], acc[i][j]);
  }
  __syncthreads();  // all GEMM1 reads of sA (vision) complete
  // + b1, gelu -> sA (in place)
  {
#pragma unroll
    for (int j2 = 0; j2 < 8; ++j2) {
      const float b = fuse_b1[c0 + j2];
#pragma unroll
      for (int i = 0; i < 4; ++i)
        sA[r0 + i][c0 + j2] = np_geluf(acc[i][j2] + b);
    }
  }
  __syncthreads();

  // GEMM2: h = gelu1 @ w2 + b2 -> sA (in place)
#pragma unroll
  for (int i = 0; i < 4; ++i)
#pragma unroll
    for (int j = 0; j < 8; ++j) acc[i][j] = 0.0f;
  gemm_acc(sA, fuse_w2, r0, c0, acc);
  __syncthreads();  // all GEMM2 reads of sA (gelu1) complete
  {
#pragma unroll
    for (int j2 = 0; j2 < 8; ++j2) {
      const float b = fuse_b2[c0 + j2];
#pragma unroll
      for (int i = 0; i < 4; ++i) sA[r0 + i][c0 + j2] = acc[i][j2] + b;
    }
  }
  __syncthreads();

  // LN stats, numpy pairwise, 8 lanes per row (exact np order)
  {
    const int r = tid >> 3, j = tid & 7;
    const float* hrow = &sA[r][0];
    const float mu =
        np_sum256_par8([&](int i) { return hrow[i]; }, j) / 256.0f;
    const float var = np_sum256_par8(
                          [&](int i) {
                            const float d = hrow[i] - mu;
                            return d * d;
                          },
                          j) /
                      256.0f;
    if (j == 0) {
      sMu[r] = mu;
      sRstd[r] = 1.0f / sqrtf(var + 1e-5f);
    }
  }
  __syncthreads();

  // oh = ((h-mu)*rstd)*g + b -> sA (column-parallel, each thread owns col tid)
  {
    const float lg = obj_ln_g[tid], lb = obj_ln_b[tid];
    for (int r = 0; r < 32; ++r) {
      const float t = (sA[r][tid] - sMu[r]) * sRstd[r];
      sA[r][tid] = t * lg + lb;
    }
  }
  __syncthreads();

  // obj head GEMM: q = gelu(oh @ ow1 + ob1) -> sA (in place)
#pragma unroll
  for (int i = 0; i < 4; ++i)
#pragma unroll
    for (int j = 0; j < 8; ++j) acc[i][j] = 0.0f;
  gemm_acc(sA, obj_w1, r0, c0, acc);
  __syncthreads();  // all obj-GEMM reads of sA (oh) complete
  {
#pragma unroll
    for (int j2 = 0; j2 < 8; ++j2) {
      const float b = obj_b1[c0 + j2];
#pragma unroll
      for (int i = 0; i < 4; ++i)
        sA[r0 + i][c0 + j2] = np_geluf(acc[i][j2] + b);
    }
  }
  __syncthreads();

  // logit = (q . ow2) + ob2, sequential ascending fma (np semantics).
  if ((tid & 7) == 0) {
    const int row = tid >> 3;
    const float* q = &sA[row][0];
    float L = 0.0f;
    for (int k = 0; k < D; ++k) L = fmaf(q[k], obj_w2[k], L);
    L = L + obj_b2[0];
    g_obj[(size_t)blk * 32 + row] = np_sigmoidf(L);
  }
}

// ---------------------------------------------------------------------------
// K2: per-batch top-100 via 128-group max tournament. Group g = elements
// {g + 128*j}; init reads are lane-consecutive (conflict-free). Per round:
// wave0 scans 128 group maxima, extracts winner (np tie semantics via packed
// key), zeroes it, recomputes only the winner's group.
// ---------------------------------------------------------------------------
__global__ __launch_bounds__(256) void k2_topk(float* __restrict__ out_scores) {
  const int b = blockIdx.x, tid = threadIdx.x;
  __shared__ ull sKey[TOK_T];
  __shared__ ull sGmax[128];
  __shared__ int sWin;
  for (int i = tid; i < TOK_T; i += 256) {
    const float s = g_obj[b * TOK_T + i];
    sKey[i] = ((ull)__float_as_uint(s) << 32) | (unsigned)(TOK_T - 1 - i);
  }
  __syncthreads();
  // init group maxima: thread t<128 scans its strided group (lane-consecutive)
  if (tid < 128) {
    ull m = 0ull;
    for (int j = 0; j < 64; ++j) {
      const ull v = sKey[tid + 128 * j];
      m = v > m ? v : m;
    }
    sGmax[tid] = m;
  }
  __syncthreads();
  for (int r = 0; r < KSEL; ++r) {
    if (tid < 64) {
      ull m = sGmax[tid];
      const ull o = sGmax[64 + tid];
      if (o > m) m = o;
#pragma unroll
      for (int off = 32; off > 0; off >>= 1) {
        const ull o2 = __shfl_down(m, off, 64);
        if (o2 > m) m = o2;
      }
      if (tid == 0) {
        const int idx = (TOK_T - 1) - (int)(unsigned)(m & 0xFFFFFFFFull);
        out_scores[b * KSEL + r] = __uint_as_float((unsigned)(m >> 32));
        g_sel[b * KSEL + r] = idx;
        sKey[idx] = 0ull;
        sWin = idx & 127;
      }
    }
    __syncthreads();
    if (tid < 64) {
      const int g = sWin;
      ull v = sKey[g + 128 * tid];
#pragma unroll
      for (int off = 32; off > 0; off >>= 1) {
        const ull o = __shfl_down(v, off, 64);
        if (o > v) v = o;
      }
      if (tid == 0) sGmax[g] = v;
    }
    __syncthreads();
  }
}

// ---------------------------------------------------------------------------
// K3: box head + text scores for the 1600 selected tokens, np-f32 semantics.
// 8 tokens/block, 256 threads (thread = output column); stats 8 lanes/row.
// ---------------------------------------------------------------------------
__global__ __launch_bounds__(256) void k3_box(
    const float* __restrict__ vision, const float* __restrict__ fuse_w1,
    const float* __restrict__ fuse_b1, const float* __restrict__ fuse_w2,
    const float* __restrict__ fuse_b2, const float* __restrict__ box_ln_g,
    const float* __restrict__ box_ln_b, const float* __restrict__ box_w1,
    const float* __restrict__ box_b1, const float* __restrict__ box_w2,
    const float* __restrict__ box_b2, float* __restrict__ out) {
#pragma clang fp contract(off)
  const int tid = threadIdx.x, c = tid;
  __shared__ float sV[8][PD];    // vision -> q(box)
  __shared__ float sG[8][PD];    // gelu1 -> bh
  __shared__ float sH[8][PD];    // h
  __shared__ float sTx[8][PD];   // per-token txt row
  __shared__ float sMu[8], sRstd[8];
  __shared__ int sIdx[8], sBat[8];
  if (tid < 8) {
    const int e = blockIdx.x * 8 + tid;
    sBat[tid] = e / KSEL;
    sIdx[tid] = g_sel[e];
  }
  __syncthreads();
  {
    const int u = tid >> 5, col = (tid & 31) * 8;
    const float* src = vision + ((size_t)sBat[u] * TOK_T + sIdx[u]) * D + col;
    *(float4*)&sV[u][col] = *(const float4*)src;
    *(float4*)&sV[u][col + 4] = *(const float4*)(src + 4);
    const float* tsrc = &g_txt[sBat[u] * D + col];
    *(float4*)&sTx[u][col] = *(const float4*)tsrc;
    *(float4*)&sTx[u][col + 4] = *(const float4*)(tsrc + 4);
  }
  __syncthreads();

  float acc[8];
#pragma unroll
  for (int u = 0; u < 8; ++u) acc[u] = 0.0f;
  // GEMM1: k = 0..255 vision, then k = 256..511 text (ascending)
  for (int k = 0; k < D; ++k) {
    const float w = fuse_w1[k * D + c];
#pragma unroll
    for (int u = 0; u < 8; ++u) acc[u] = fmaf(sV[u][k], w, acc[u]);
  }
  for (int k = 0; k < D; ++k) {
    const float w = fuse_w1[(D + k) * D + c];
#pragma unroll
    for (int u = 0; u < 8; ++u) acc[u] = fmaf(sTx[u][k], w, acc[u]);
  }
  {
    const float b = fuse_b1[c];
#pragma unroll
    for (int u = 0; u < 8; ++u) sG[u][c] = np_geluf(acc[u] + b);
  }
  __syncthreads();

  // GEMM2 -> h
#pragma unroll
  for (int u = 0; u < 8; ++u) acc[u] = 0.0f;
  for (int k = 0; k < D; ++k) {
    const float w = fuse_w2[k * D + c];
#pragma unroll
    for (int u = 0; u < 8; ++u) acc[u] = fmaf(sG[u][k], w, acc[u]);
  }
  {
    const float b = fuse_b2[c];
#pragma unroll
    for (int u = 0; u < 8; ++u) sH[u][c] = acc[u] + b;
  }
  __syncthreads();

  // per-token stats (np pairwise), 8 lanes per row; rows 0..7 on wave 0/1
  {
    const int u = tid >> 3, j = tid & 7;
    if (u < 8) {
      const float* h = &sH[u][0];
      const float* tx = &sTx[u][0];
      const float mu = np_sum256_par8([&](int i) { return h[i]; }, j) / 256.0f;
      const float var = np_sum256_par8(
                            [&](int i) {
                              const float d = h[i] - mu;
                              return d * d;
                            },
                            j) /
                        256.0f;
      const float q2 = np_sum256_par8([&](int i) { return h[i] * h[i]; }, j);
      const float den = sqrtf(q2 + 1e-12f);
      const float ts =
          np_sum256_par8([&](int i) { return (h[i] / den) * tx[i]; }, j);
      if (j == 0) {
        sMu[u] = mu;
        sRstd[u] = 1.0f / sqrtf(var + 1e-5f);
        out[8000 + blockIdx.x * 8 + u] = ts;
      }
    }
  }
  __syncthreads();

  // bh -> sG
  {
    const float lg = box_ln_g[c], lb = box_ln_b[c];
#pragma unroll
    for (int u = 0; u < 8; ++u) {
      const float t = (sH[u][c] - sMu[u]) * sRstd[u];
      sG[u][c] = t * lg + lb;
    }
  }
  __syncthreads();

  // box GEMM: q = gelu(bh @ bw1 + bb1) -> sV
#pragma unroll
  for (int u = 0; u < 8; ++u) acc[u] = 0.0f;
  for (int k = 0; k < D; ++k) {
    const float w = box_w1[k * D + c];
#pragma unroll
    for (int u = 0; u < 8; ++u) acc[u] = fmaf(sG[u][k], w, acc[u]);
  }
  {
    const float b = box_b1[c];
#pragma unroll
    for (int u = 0; u < 8; ++u) sV[u][c] = np_geluf(acc[u] + b);
  }
  __syncthreads();

  // logits: sequential ascending fma per (token, j), then + b2, sigmoid
  if (tid < 32) {
    const int u = tid >> 2, j = tid & 3;
    const float* q = &sV[u][0];
    float L = 0.0f;
    for (int k = 0; k < D; ++k) L = fmaf(q[k], box_w2[k * 4 + j], L);
    L = L + box_b2[j];
    out[(blockIdx.x * 8 + u) * 4 + j] = np_sigmoidf(L);
  }
}

extern "C" void kernel_launch(void* const* d_in, const int* in_sizes, int n_in,
                              void* d_out, int out_size, void* d_ws,
                              size_t ws_size, hipStream_t stream) {
  const float* vision   = (const float*)d_in[0];
  const float* text_emb = (const float*)d_in[1];
  const float* fuse_w1  = (const float*)d_in[2];
  const float* fuse_b1  = (const float*)d_in[3];
  const float* fuse_w2  = (const float*)d_in[4];
  const float* fuse_b2  = (const float*)d_in[5];
  const float* box_ln_g = (const float*)d_in[6];
  const float* box_ln_b = (const float*)d_in[7];
  const float* box_w1   = (const float*)d_in[8];
  const float* box_b1   = (const float*)d_in[9];
  const float* box_w2   = (const float*)d_in[10];
  const float* box_b2   = (const float*)d_in[11];
  const float* obj_ln_g = (const float*)d_in[12];
  const float* obj_ln_b = (const float*)d_in[13];
  const float* obj_w1   = (const float*)d_in[14];
  const float* obj_b1   = (const float*)d_in[15];
  const float* obj_w2   = (const float*)d_in[16];
  const float* obj_b2   = (const float*)d_in[17];
  float* out = (float*)d_out;

  k0_txt<<<TOK_B, 256, 0, stream>>>(text_emb);
  k1_obj<<<NTOK / 32, 256, 0, stream>>>(
      vision, fuse_w1, fuse_b1, fuse_w2, fuse_b2, obj_ln_g, obj_ln_b, obj_w1,
      obj_b1, obj_w2, obj_b2);
  k2_topk<<<TOK_B, 256, 0, stream>>>(out + 6400);
  k3_box<<<(TOK_B * KSEL) / 8, 256, 0, stream>>>(
      vision, fuse_w1, fuse_b1, fuse_w2, fuse_b2, box_ln_g, box_ln_b, box_w1,
      box_b1, box_w2, box_b2, out);
}